// Round 4
// baseline (182.402 us; speedup 1.0000x reference)
//
#include <hip/hip_runtime.h>

// Problem constants (fixed by setup_inputs)
#define B_    4
#define C_    128
#define CQ_   16
#define N_    4096
#define SPLIT 4
#define MPER  (N_ / SPLIT)   // 1024 kv-positions per split block

typedef short          s16x8 __attribute__((ext_vector_type(8)));
typedef unsigned short u16x4 __attribute__((ext_vector_type(4)));
typedef unsigned int   u32x4 __attribute__((ext_vector_type(4)));
typedef float          f32x4 __attribute__((ext_vector_type(4)));
typedef unsigned short u16;
typedef unsigned int   u32;

__device__ __forceinline__ u16 f2bf(float f) {
    unsigned int u = __builtin_bit_cast(unsigned int, f);
    u += 0x7fffu + ((u >> 16) & 1u);           // round-to-nearest-even
    return (u16)(u >> 16);
}
__device__ __forceinline__ float bf2f(u16 h) {
    unsigned int u = ((unsigned int)h) << 16;
    return __builtin_bit_cast(float, u);
}
__device__ __forceinline__ s16x8 ld8bf(const u16* p) {
    return *reinterpret_cast<const s16x8*>(p);
}
__device__ __forceinline__ u32 cvtpk_bf16(float lo, float hi) {
    u32 r;
    asm("v_cvt_pk_bf16_f32 %0, %1, %2" : "=v"(r) : "v"(lo), "v"(hi));
    return r;
}

// ---------------------------------------------------------------------------
// Fused projections, one launch (z=0: q&k, z=1..4: v chunk of 32 channels).
// ---------------------------------------------------------------------------
__global__ __launch_bounds__(256) void proj_all_kernel(
    const float* __restrict__ x,
    const float* __restrict__ wq, const float* __restrict__ bq,
    const float* __restrict__ wk, const float* __restrict__ bk,
    const float* __restrict__ wv, const float* __restrict__ bv,
    u16* __restrict__ Qb, u16* __restrict__ Kb, u16* __restrict__ Vb)
{
    __shared__ float smem[12800];   // 51.2 KB, carved per-branch
    const int tid = threadIdx.x;
    const int b   = blockIdx.y;
    const int nl  = tid & 63;
    const int n   = blockIdx.x * 64 + nl;
    const int ch  = tid >> 6;
    const float* xp = x + ((size_t)b * C_) * N_ + n;

    if (blockIdx.z == 0) {
        // ---------------- q & k projection ----------------
        float* wqs = smem;               // 2048
        float* wks = smem + 2048;        // 2048
        float (*part)[4][64][17] = (float (*)[4][64][17])(smem + 4096);
        for (int i = tid; i < CQ_ * C_; i += 256) { wqs[i] = wq[i]; wks[i] = wk[i]; }
        __syncthreads();

        float qa[CQ_], ka[CQ_];
#pragma unroll
        for (int j = 0; j < CQ_; ++j) { qa[j] = 0.f; ka[j] = 0.f; }
        const int c0 = ch * 32;
        for (int c = c0; c < c0 + 32; ++c) {
            const float xv = xp[(size_t)c * N_];
#pragma unroll
            for (int j = 0; j < CQ_; ++j) {
                qa[j] = fmaf(wqs[j * C_ + c], xv, qa[j]);
                ka[j] = fmaf(wks[j * C_ + c], xv, ka[j]);
            }
        }
#pragma unroll
        for (int j = 0; j < CQ_; ++j) { part[0][ch][nl][j] = qa[j]; part[1][ch][nl][j] = ka[j]; }
        __syncthreads();

        if (tid < 128) {
            const int which = tid >> 6;        // 0 -> q, 1 -> k
            const int n2 = tid & 63;
            const float* bias = which ? bk : bq;
            alignas(16) u16 row[32];
#pragma unroll
            for (int j = 0; j < CQ_; ++j) {
                float v = part[which][0][n2][j] + part[which][1][n2][j]
                        + part[which][2][n2][j] + part[which][3][n2][j] + bias[j];
                u16 h = f2bf(v);
                row[j]       = h;
                row[CQ_ + j] = f2bf(v - bf2f(h));   // lo residual
            }
            u16* dst = (which ? Kb : Qb) + ((size_t)(b * N_ + blockIdx.x * 64 + n2)) * 32;
#pragma unroll
            for (int i = 0; i < 4; ++i)
                reinterpret_cast<uint4*>(dst)[i] = reinterpret_cast<const uint4*>(row)[i];
        }
    } else {
        // ---------------- v projection (32 channels) ----------------
        const int cv0 = (blockIdx.z - 1) * 32;
        float* wvs = smem;               // 4096
        float (*part)[64][33] = (float (*)[64][33])(smem + 4096);
        for (int i = tid; i < 32 * C_; i += 256) wvs[i] = wv[cv0 * C_ + i];
        __syncthreads();

        float acc[32];
#pragma unroll
        for (int j = 0; j < 32; ++j) acc[j] = 0.f;
        const int c0 = ch * 32;
        for (int c = c0; c < c0 + 32; ++c) {
            const float xv = xp[(size_t)c * N_];
#pragma unroll
            for (int j = 0; j < 32; ++j) acc[j] = fmaf(wvs[j * C_ + c], xv, acc[j]);
        }
#pragma unroll
        for (int j = 0; j < 32; ++j) part[ch][nl][j] = acc[j];
        __syncthreads();

        const int jq = tid >> 6;
#pragma unroll
        for (int jj = 0; jj < 8; ++jj) {
            const int j = jq * 8 + jj;
            float v = part[0][nl][j] + part[1][nl][j] + part[2][nl][j] + part[3][nl][j]
                    + bv[cv0 + j];
            Vb[((size_t)(b * C_ + cv0 + j)) * N_ + blockIdx.x * 64 + nl] = f2bf(v);
        }
    }
}

// ---------------------------------------------------------------------------
// Split-KV fused attention — barrier-free, LDS-free.
// Each wave owns 16 q-cols with the FULL C=128 output. The S->P relayout
// (lane holds rows 4g..4g+3 of a 32-row slice; PV B-frag needs rows 8g..8g+7)
// is pure lane-permute, done with __shfl_xor only (verified lane algebra):
//   source lanes hold packed pairs a0/b0 (chunk A rows 4g..4g+3) and
//   a1/b1 (chunk B rows 16+4g..16+4g+3).
//   m  = shfl_xor((g>=2)? a0 : a1, 32)   // source-side select!
//   eA = (g in {1,2}) ? m : ((g>=2)? a1 : a0)    // own fragment
//   vA = (g in {1,2}) ? own : m                  // what the ^16 partner needs
//   xA = shfl_xor(vA, 16)
//   w  = even g ? {eA,eB,xA,xB} : {xA,xB,eA,eB}
// Round-3 bug fixed: shuffled vars are now selected by the SOURCE lane's
// group (the ^16 partner has opposite g-parity, so target-side selection
// shipped the wrong register).
// ---------------------------------------------------------------------------
__global__ __launch_bounds__(256) void attn_split_kernel(
    const u16* __restrict__ Qb, const u16* __restrict__ Kb, const u16* __restrict__ Vb,
    u16* __restrict__ Opart, float* __restrict__ Lpart)
{
    const int tid  = threadIdx.x;
    const int lane = tid & 63;
    const int l16  = lane & 15;
    const int g    = lane >> 4;       // 0..3
    const int wave = tid >> 6;        // 0..3 — owns q-cols n0+16*wave..+15
    const int b    = blockIdx.y;
    const int n0   = blockIdx.x * 64;
    const int s    = blockIdx.z;
    const int ms   = s * MPER;

    // Q B-fragment: B[k=d][col=n], d = 8g..8g+7 of [hi|lo]
    const int qn = n0 + wave * 16 + l16;
    const s16x8 qf = ld8bf(Qb + ((size_t)(b * N_ + qn)) * 32 + 8 * g);

    const u16* kbase = Kb + ((size_t)b * N_ + l16) * 32;
    const u16* vbase = Vb + ((size_t)(b * C_ + l16)) * N_ + 8 * g;

    const bool hig = (g >= 2);
    const bool mid = (g == 1) || (g == 2);

    f32x4 acc[8];
#pragma unroll
    for (int cg = 0; cg < 8; ++cg) acc[cg] = {};
    float lpart = 0.f;

    for (int t = 0; t < MPER / 64; ++t) {
        const int m0 = ms + t * 64;

        // ---- S^T = K . Q^T (4 tiles of 16 kv-rows x 16 q-cols) ----
        f32x4 sacc[4];
#pragma unroll
        for (int mg = 0; mg < 4; ++mg) {
            const u16* kr = kbase + (size_t)(m0 + 16 * mg) * 32;
            s16x8 kf1 = ld8bf(kr + 8 * (g & 1));            // [Kh | Kh]
            s16x8 kf2 = {};                                  // [Kl | 0 ]
            if (g < 2) kf2 = ld8bf(kr + 16 + 8 * g);
            f32x4 z = {};
            z = __builtin_amdgcn_mfma_f32_16x16x32_bf16(kf1, qf, z, 0, 0, 0);
            z = __builtin_amdgcn_mfma_f32_16x16x32_bf16(kf2, qf, z, 0, 0, 0);
            sacc[mg] = z;
        }

        // ---- P = exp(S^T); accumulate denominator (pre-round f32) ----
        float p[4][4];
#pragma unroll
        for (int mg = 0; mg < 4; ++mg) {
#pragma unroll
            for (int i = 0; i < 4; ++i) {
                p[mg][i] = __expf(sacc[mg][i]);
                lpart += p[mg][i];
            }
        }

        // ---- per 32-row slice: relayout P in-register, then PV MFMAs ----
#pragma unroll
        for (int ss = 0; ss < 2; ++ss) {
            const u32 a0 = cvtpk_bf16(p[2 * ss][0],     p[2 * ss][1]);      // rows 4g,4g+1   (chunk A)
            const u32 b0 = cvtpk_bf16(p[2 * ss][2],     p[2 * ss][3]);      // rows 4g+2,4g+3 (chunk A)
            const u32 a1 = cvtpk_bf16(p[2 * ss + 1][0], p[2 * ss + 1][1]);  // rows 16+4g,+1  (chunk B)
            const u32 b1 = cvtpk_bf16(p[2 * ss + 1][2], p[2 * ss + 1][3]);  // rows 16+4g+2,+3(chunk B)

            const u32 mA = (u32)__shfl_xor((int)(hig ? a0 : a1), 32);
            const u32 mB = (u32)__shfl_xor((int)(hig ? b0 : b1), 32);
            const u32 oA = hig ? a1 : a0;
            const u32 oB = hig ? b1 : b0;
            const u32 eA = mid ? mA : oA;
            const u32 eB = mid ? mB : oB;
            const u32 vA = mid ? oA : mA;
            const u32 vB = mid ? oB : mB;
            const u32 xA = (u32)__shfl_xor((int)vA, 16);
            const u32 xB = (u32)__shfl_xor((int)vB, 16);
            u32x4 w;
            w[0] = (g & 1) ? xA : eA;
            w[1] = (g & 1) ? xB : eB;
            w[2] = (g & 1) ? eA : xA;
            w[3] = (g & 1) ? eB : xB;
            const s16x8 pf = __builtin_bit_cast(s16x8, w);
#pragma unroll
            for (int cg = 0; cg < 8; ++cg) {
                const s16x8 vf = ld8bf(vbase + (size_t)(16 * cg) * N_ + m0 + 32 * ss);
                acc[cg] = __builtin_amdgcn_mfma_f32_16x16x32_bf16(vf, pf, acc[cg], 0, 0, 0);
            }
        }
    }

    // ---- epilogue: store partial l and unnormalized partial O (bf16) ----
    lpart += __shfl_xor(lpart, 16);
    lpart += __shfl_xor(lpart, 32);
    const size_t sb = (size_t)(s * B_ + b);
    if (lane < 16) Lpart[sb * N_ + n0 + wave * 16 + l16] = lpart;

    const int n = n0 + wave * 16 + l16;
#pragma unroll
    for (int cg = 0; cg < 8; ++cg) {
#pragma unroll
        for (int i = 0; i < 4; ++i) {
            const int c = 16 * cg + 4 * g + i;
            Opart[(sb * C_ + c) * N_ + n] = f2bf(acc[cg][i]);
        }
    }
}

// ---------------------------------------------------------------------------
// Combine splits: out = gamma * (sum_s Opart) / (sum_s Lpart) + x.
// ---------------------------------------------------------------------------
__global__ __launch_bounds__(256) void reduce_kernel(
    const u16* __restrict__ Opart, const float* __restrict__ Lpart,
    const float* __restrict__ x, const float* __restrict__ gamma,
    float* __restrict__ out)
{
    const int t  = blockIdx.x * 256 + threadIdx.x;      // 524288 threads
    const size_t e0 = (size_t)t * 4;                    // < B*C*N = 2^21
    const int n = (int)(e0 & (N_ - 1));
    const int c = (int)((e0 >> 12) & (C_ - 1));
    const int b = (int)(e0 >> 19);

    float o0 = 0.f, o1 = 0.f, o2 = 0.f, o3 = 0.f;
    f32x4 l = {};
#pragma unroll
    for (int s = 0; s < SPLIT; ++s) {
        const size_t sb = (size_t)(s * B_ + b);
        const u16x4 ov = *reinterpret_cast<const u16x4*>(Opart + (sb * C_ + c) * N_ + n);
        const f32x4 lv = *reinterpret_cast<const f32x4*>(Lpart + sb * N_ + n);
        o0 += bf2f(ov[0]); o1 += bf2f(ov[1]); o2 += bf2f(ov[2]); o3 += bf2f(ov[3]);
        l += lv;
    }
    const float gm = gamma[0];
    const f32x4 xv = *reinterpret_cast<const f32x4*>(x + e0);
    f32x4 r;
    r[0] = gm * o0 / l[0] + xv[0];
    r[1] = gm * o1 / l[1] + xv[1];
    r[2] = gm * o2 / l[2] + xv[2];
    r[3] = gm * o3 / l[3] + xv[3];
    *reinterpret_cast<f32x4*>(out + e0) = r;
}

// ---------------------------------------------------------------------------
extern "C" void kernel_launch(void* const* d_in, const int* in_sizes, int n_in,
                              void* d_out, int out_size, void* d_ws, size_t ws_size,
                              hipStream_t stream)
{
    const float* x     = (const float*)d_in[0];
    const float* wq    = (const float*)d_in[1];
    const float* bq    = (const float*)d_in[2];
    const float* wk    = (const float*)d_in[3];
    const float* bk    = (const float*)d_in[4];
    const float* wv    = (const float*)d_in[5];
    const float* bv    = (const float*)d_in[6];
    const float* gamma = (const float*)d_in[7];
    float* out = (float*)d_out;

    // ws layout (~22.5 MB): Qb 1MB | Kb 1MB | Vb 4MB | Opart 16MB | Lpart 256KB
    u16* Qb = (u16*)d_ws;                               // (B,N,32)  [hi|lo]
    u16* Kb = Qb + (size_t)B_ * N_ * 32;                // (B,N,32)  [hi|lo]
    u16* Vb = Kb + (size_t)B_ * N_ * 32;                // (B,C,N)   bf16
    u16* Opart = Vb + (size_t)B_ * C_ * N_;             // (SPLIT,B,C,N) bf16
    float* Lpart = (float*)(Opart + (size_t)SPLIT * B_ * C_ * N_);  // (SPLIT,B,N)

    proj_all_kernel<<<dim3(N_ / 64, B_, 5), 256, 0, stream>>>(
        x, wq, bq, wk, bk, wv, bv, Qb, Kb, Vb);
    attn_split_kernel<<<dim3(N_ / 64, B_, SPLIT), 256, 0, stream>>>(
        Qb, Kb, Vb, Opart, Lpart);
    reduce_kernel<<<(B_ * C_ * N_ / 4) / 256, 256, 0, stream>>>(
        Opart, Lpart, x, gamma, out);
}

// Round 6
// 180.503 us; speedup vs baseline: 1.0105x; 1.0105x over previous
//
#include <hip/hip_runtime.h>

// Problem constants (fixed by setup_inputs)
#define B_    4
#define C_    128
#define CQ_   16
#define N_    4096
#define SPLIT 4
#define MPER  (N_ / SPLIT)   // 1024 kv-positions per split block

typedef short          s16x8 __attribute__((ext_vector_type(8)));
typedef unsigned short u16x4 __attribute__((ext_vector_type(4)));
typedef unsigned int   u32x4 __attribute__((ext_vector_type(4)));
typedef float          f32x4 __attribute__((ext_vector_type(4)));
typedef unsigned short u16;
typedef unsigned int   u32;

__device__ __forceinline__ u16 f2bf(float f) {
    unsigned int u = __builtin_bit_cast(unsigned int, f);
    u += 0x7fffu + ((u >> 16) & 1u);           // round-to-nearest-even
    return (u16)(u >> 16);
}
__device__ __forceinline__ float bf2f(u16 h) {
    unsigned int u = ((unsigned int)h) << 16;
    return __builtin_bit_cast(float, u);
}
__device__ __forceinline__ s16x8 ld8bf(const u16* p) {
    return *reinterpret_cast<const s16x8*>(p);
}
__device__ __forceinline__ u32 cvtpk_bf16(float lo, float hi) {
    u32 r;
    asm("v_cvt_pk_bf16_f32 %0, %1, %2" : "=v"(r) : "v"(lo), "v"(hi));
    return r;
}

// ---------------------------------------------------------------------------
// Fused projections, one launch (z=0: q&k, z=1..4: v chunk of 32 channels).
// ---------------------------------------------------------------------------
__global__ __launch_bounds__(256) void proj_all_kernel(
    const float* __restrict__ x,
    const float* __restrict__ wq, const float* __restrict__ bq,
    const float* __restrict__ wk, const float* __restrict__ bk,
    const float* __restrict__ wv, const float* __restrict__ bv,
    u16* __restrict__ Qb, u16* __restrict__ Kb, u16* __restrict__ Vb)
{
    __shared__ float smem[12800];   // 51.2 KB, carved per-branch
    const int tid = threadIdx.x;
    const int b   = blockIdx.y;
    const int nl  = tid & 63;
    const int n   = blockIdx.x * 64 + nl;
    const int ch  = tid >> 6;
    const float* xp = x + ((size_t)b * C_) * N_ + n;

    if (blockIdx.z == 0) {
        // ---------------- q & k projection ----------------
        float* wqs = smem;               // 2048
        float* wks = smem + 2048;        // 2048
        float (*part)[4][64][17] = (float (*)[4][64][17])(smem + 4096);
        for (int i = tid; i < CQ_ * C_; i += 256) { wqs[i] = wq[i]; wks[i] = wk[i]; }
        __syncthreads();

        float qa[CQ_], ka[CQ_];
#pragma unroll
        for (int j = 0; j < CQ_; ++j) { qa[j] = 0.f; ka[j] = 0.f; }
        const int c0 = ch * 32;
        for (int c = c0; c < c0 + 32; ++c) {
            const float xv = xp[(size_t)c * N_];
#pragma unroll
            for (int j = 0; j < CQ_; ++j) {
                qa[j] = fmaf(wqs[j * C_ + c], xv, qa[j]);
                ka[j] = fmaf(wks[j * C_ + c], xv, ka[j]);
            }
        }
#pragma unroll
        for (int j = 0; j < CQ_; ++j) { part[0][ch][nl][j] = qa[j]; part[1][ch][nl][j] = ka[j]; }
        __syncthreads();

        if (tid < 128) {
            const int which = tid >> 6;        // 0 -> q, 1 -> k
            const int n2 = tid & 63;
            const float* bias = which ? bk : bq;
            alignas(16) u16 row[32];
#pragma unroll
            for (int j = 0; j < CQ_; ++j) {
                float v = part[which][0][n2][j] + part[which][1][n2][j]
                        + part[which][2][n2][j] + part[which][3][n2][j] + bias[j];
                u16 h = f2bf(v);
                row[j]       = h;
                row[CQ_ + j] = f2bf(v - bf2f(h));   // lo residual
            }
            u16* dst = (which ? Kb : Qb) + ((size_t)(b * N_ + blockIdx.x * 64 + n2)) * 32;
#pragma unroll
            for (int i = 0; i < 4; ++i)
                reinterpret_cast<uint4*>(dst)[i] = reinterpret_cast<const uint4*>(row)[i];
        }
    } else {
        // ---------------- v projection (32 channels) ----------------
        const int cv0 = (blockIdx.z - 1) * 32;
        float* wvs = smem;               // 4096
        float (*part)[64][33] = (float (*)[64][33])(smem + 4096);
        for (int i = tid; i < 32 * C_; i += 256) wvs[i] = wv[cv0 * C_ + i];
        __syncthreads();

        float acc[32];
#pragma unroll
        for (int j = 0; j < 32; ++j) acc[j] = 0.f;
        const int c0 = ch * 32;
        for (int c = c0; c < c0 + 32; ++c) {
            const float xv = xp[(size_t)c * N_];
#pragma unroll
            for (int j = 0; j < 32; ++j) acc[j] = fmaf(wvs[j * C_ + c], xv, acc[j]);
        }
#pragma unroll
        for (int j = 0; j < 32; ++j) part[ch][nl][j] = acc[j];
        __syncthreads();

        const int jq = tid >> 6;
#pragma unroll
        for (int jj = 0; jj < 8; ++jj) {
            const int j = jq * 8 + jj;
            float v = part[0][nl][j] + part[1][nl][j] + part[2][nl][j] + part[3][nl][j]
                    + bv[cv0 + j];
            Vb[((size_t)(b * C_ + cv0 + j)) * N_ + blockIdx.x * 64 + nl] = f2bf(v);
        }
    }
}

// ---------------------------------------------------------------------------
// Split-KV fused attention — barrier-free, LDS-free. Identical math to the
// PASSING round-4 kernel (__expf, no Q prescale; relayout lane algebra
// verified). Perf changes only:
//   * __launch_bounds__(256,4): VGPR cap 48 -> 128 (grid caps us at 4
//     blocks/CU anyway, so no occupancy loss).
//   * K-frags + first V-batch loads hoisted before QK; second V-batch issued
//     right after QK so its latency overlaps exp+relayout+first PV.
// Round-4 diagnosis: 48 VGPRs forced every ld8bf into load->vmcnt(0)->use
// (~22 serialized L2 hits/iter ~= 5500 cyc, matching 150 us).
// ---------------------------------------------------------------------------
__global__ __launch_bounds__(256, 4) void attn_split_kernel(
    const u16* __restrict__ Qb, const u16* __restrict__ Kb, const u16* __restrict__ Vb,
    u16* __restrict__ Opart, float* __restrict__ Lpart)
{
    const int tid  = threadIdx.x;
    const int lane = tid & 63;
    const int l16  = lane & 15;
    const int g    = lane >> 4;       // 0..3
    const int wave = tid >> 6;        // 0..3 — owns q-cols n0+16*wave..+15
    const int b    = blockIdx.y;
    const int n0   = blockIdx.x * 64;
    const int s    = blockIdx.z;
    const int ms   = s * MPER;

    // Q B-fragment: B[k=d][col=n], d = 8g..8g+7 of [hi|lo]
    const int qn = n0 + wave * 16 + l16;
    const s16x8 qf = ld8bf(Qb + ((size_t)(b * N_ + qn)) * 32 + 8 * g);

    const u16* kbase = Kb + ((size_t)b * N_ + l16) * 32;
    const u16* vbase = Vb + ((size_t)(b * C_ + l16)) * N_ + 8 * g;

    const bool hig = (g >= 2);
    const bool mid = (g == 1) || (g == 2);

    f32x4 acc[8];
#pragma unroll
    for (int cg = 0; cg < 8; ++cg) acc[cg] = {};
    float lpart = 0.f;

    for (int t = 0; t < MPER / 64; ++t) {
        const int m0 = ms + t * 64;

        // ---- hoist K-frag + first V-batch loads (latency overlaps QK) ----
        s16x8 kf1[4], kf2[4];
#pragma unroll
        for (int mg = 0; mg < 4; ++mg) {
            const u16* kr = kbase + (size_t)(m0 + 16 * mg) * 32;
            kf1[mg] = ld8bf(kr + 8 * (g & 1));              // [Kh | Kh]
            kf2[mg] = {};                                    // [Kl | 0 ]
            if (g < 2) kf2[mg] = ld8bf(kr + 16 + 8 * g);
        }
        s16x8 vf0[8];
#pragma unroll
        for (int cg = 0; cg < 8; ++cg)
            vf0[cg] = ld8bf(vbase + (size_t)(16 * cg) * N_ + m0);

        // ---- S^T = K . Q^T (4 tiles of 16 kv-rows x 16 q-cols) ----
        f32x4 sacc[4];
#pragma unroll
        for (int mg = 0; mg < 4; ++mg) {
            f32x4 z = {};
            z = __builtin_amdgcn_mfma_f32_16x16x32_bf16(kf1[mg], qf, z, 0, 0, 0);
            z = __builtin_amdgcn_mfma_f32_16x16x32_bf16(kf2[mg], qf, z, 0, 0, 0);
            sacc[mg] = z;
        }

        // ---- issue second V-batch; latency hides under exp+relayout+PV0 ----
        s16x8 vf1[8];
#pragma unroll
        for (int cg = 0; cg < 8; ++cg)
            vf1[cg] = ld8bf(vbase + (size_t)(16 * cg) * N_ + m0 + 32);

        // ---- P = exp(S^T); accumulate denominator (f32) ----
        float p[4][4];
#pragma unroll
        for (int mg = 0; mg < 4; ++mg) {
#pragma unroll
            for (int i = 0; i < 4; ++i) {
                p[mg][i] = __expf(sacc[mg][i]);
                lpart += p[mg][i];
            }
        }

        // ---- per 32-row slice: relayout P in-register, then PV MFMAs ----
#pragma unroll
        for (int ss = 0; ss < 2; ++ss) {
            const u32 a0 = cvtpk_bf16(p[2 * ss][0],     p[2 * ss][1]);      // rows 4g,4g+1   (chunk A)
            const u32 b0 = cvtpk_bf16(p[2 * ss][2],     p[2 * ss][3]);      // rows 4g+2,4g+3 (chunk A)
            const u32 a1 = cvtpk_bf16(p[2 * ss + 1][0], p[2 * ss + 1][1]);  // rows 16+4g,+1  (chunk B)
            const u32 b1 = cvtpk_bf16(p[2 * ss + 1][2], p[2 * ss + 1][3]);  // rows 16+4g+2,+3(chunk B)

            const u32 mA = (u32)__shfl_xor((int)(hig ? a0 : a1), 32);
            const u32 mB = (u32)__shfl_xor((int)(hig ? b0 : b1), 32);
            const u32 oA = hig ? a1 : a0;
            const u32 oB = hig ? b1 : b0;
            const u32 eA = mid ? mA : oA;
            const u32 eB = mid ? mB : oB;
            const u32 vA = mid ? oA : mA;
            const u32 vB = mid ? oB : mB;
            const u32 xA = (u32)__shfl_xor((int)vA, 16);
            const u32 xB = (u32)__shfl_xor((int)vB, 16);
            u32x4 w;
            w[0] = (g & 1) ? xA : eA;
            w[1] = (g & 1) ? xB : eB;
            w[2] = (g & 1) ? eA : xA;
            w[3] = (g & 1) ? eB : xB;
            const s16x8 pf = __builtin_bit_cast(s16x8, w);
#pragma unroll
            for (int cg = 0; cg < 8; ++cg) {
                const s16x8 vf = ss ? vf1[cg] : vf0[cg];
                acc[cg] = __builtin_amdgcn_mfma_f32_16x16x32_bf16(vf, pf, acc[cg], 0, 0, 0);
            }
        }
    }

    // ---- epilogue: store partial l and unnormalized partial O (bf16) ----
    lpart += __shfl_xor(lpart, 16);
    lpart += __shfl_xor(lpart, 32);
    const size_t sb = (size_t)(s * B_ + b);
    if (lane < 16) Lpart[sb * N_ + n0 + wave * 16 + l16] = lpart;

    const int n = n0 + wave * 16 + l16;
#pragma unroll
    for (int cg = 0; cg < 8; ++cg) {
#pragma unroll
        for (int i = 0; i < 4; ++i) {
            const int c = 16 * cg + 4 * g + i;
            Opart[(sb * C_ + c) * N_ + n] = f2bf(acc[cg][i]);
        }
    }
}

// ---------------------------------------------------------------------------
// Combine splits: out = gamma * (sum_s Opart) / (sum_s Lpart) + x.
// ---------------------------------------------------------------------------
__global__ __launch_bounds__(256) void reduce_kernel(
    const u16* __restrict__ Opart, const float* __restrict__ Lpart,
    const float* __restrict__ x, const float* __restrict__ gamma,
    float* __restrict__ out)
{
    const int t  = blockIdx.x * 256 + threadIdx.x;      // 524288 threads
    const size_t e0 = (size_t)t * 4;                    // < B*C*N = 2^21
    const int n = (int)(e0 & (N_ - 1));
    const int c = (int)((e0 >> 12) & (C_ - 1));
    const int b = (int)(e0 >> 19);

    float o0 = 0.f, o1 = 0.f, o2 = 0.f, o3 = 0.f;
    f32x4 l = {};
#pragma unroll
    for (int s = 0; s < SPLIT; ++s) {
        const size_t sb = (size_t)(s * B_ + b);
        const u16x4 ov = *reinterpret_cast<const u16x4*>(Opart + (sb * C_ + c) * N_ + n);
        const f32x4 lv = *reinterpret_cast<const f32x4*>(Lpart + sb * N_ + n);
        o0 += bf2f(ov[0]); o1 += bf2f(ov[1]); o2 += bf2f(ov[2]); o3 += bf2f(ov[3]);
        l += lv;
    }
    const float gm = gamma[0];
    const f32x4 xv = *reinterpret_cast<const f32x4*>(x + e0);
    f32x4 r;
    r[0] = gm * o0 / l[0] + xv[0];
    r[1] = gm * o1 / l[1] + xv[1];
    r[2] = gm * o2 / l[2] + xv[2];
    r[3] = gm * o3 / l[3] + xv[3];
    *reinterpret_cast<f32x4*>(out + e0) = r;
}

// ---------------------------------------------------------------------------
extern "C" void kernel_launch(void* const* d_in, const int* in_sizes, int n_in,
                              void* d_out, int out_size, void* d_ws, size_t ws_size,
                              hipStream_t stream)
{
    const float* x     = (const float*)d_in[0];
    const float* wq    = (const float*)d_in[1];
    const float* bq    = (const float*)d_in[2];
    const float* wk    = (const float*)d_in[3];
    const float* bk    = (const float*)d_in[4];
    const float* wv    = (const float*)d_in[5];
    const float* bv    = (const float*)d_in[6];
    const float* gamma = (const float*)d_in[7];
    float* out = (float*)d_out;

    // ws layout (~22.5 MB): Qb 1MB | Kb 1MB | Vb 4MB | Opart 16MB | Lpart 256KB
    u16* Qb = (u16*)d_ws;                               // (B,N,32)  [hi|lo]
    u16* Kb = Qb + (size_t)B_ * N_ * 32;                // (B,N,32)  [hi|lo]
    u16* Vb = Kb + (size_t)B_ * N_ * 32;                // (B,C,N)   bf16
    u16* Opart = Vb + (size_t)B_ * C_ * N_;             // (SPLIT,B,C,N) bf16
    float* Lpart = (float*)(Opart + (size_t)SPLIT * B_ * C_ * N_);  // (SPLIT,B,N)

    proj_all_kernel<<<dim3(N_ / 64, B_, 5), 256, 0, stream>>>(
        x, wq, bq, wk, bk, wv, bv, Qb, Kb, Vb);
    attn_split_kernel<<<dim3(N_ / 64, B_, SPLIT), 256, 0, stream>>>(
        Qb, Kb, Vb, Opart, Lpart);
    reduce_kernel<<<(B_ * C_ * N_ / 4) / 256, 256, 0, stream>>>(
        Opart, Lpart, x, gamma, out);
}

// Round 7
// 78.733 us; speedup vs baseline: 2.3167x; 2.2926x over previous
//
#include <hip/hip_runtime.h>

// Problem constants (fixed by setup_inputs)
#define B_    4
#define C_    128
#define CQ_   16
#define N_    4096
#define SPLIT 4
#define MPER  (N_ / SPLIT)   // 1024 kv-positions per split block
#define KVBLK 64

typedef short          s16x8 __attribute__((ext_vector_type(8)));
typedef unsigned short u16x4 __attribute__((ext_vector_type(4)));
typedef unsigned int   u32x4 __attribute__((ext_vector_type(4)));
typedef float          f32x4 __attribute__((ext_vector_type(4)));
typedef unsigned short u16;
typedef unsigned int   u32;

__device__ __forceinline__ u16 f2bf(float f) {
    unsigned int u = __builtin_bit_cast(unsigned int, f);
    u += 0x7fffu + ((u >> 16) & 1u);           // round-to-nearest-even
    return (u16)(u >> 16);
}
__device__ __forceinline__ float bf2f(u16 h) {
    unsigned int u = ((unsigned int)h) << 16;
    return __builtin_bit_cast(float, u);
}
__device__ __forceinline__ s16x8 ld8bf(const u16* p) {
    return *reinterpret_cast<const s16x8*>(p);
}
__device__ __forceinline__ u32 cvtpk_bf16(float lo, float hi) {
    u32 r;
    asm("v_cvt_pk_bf16_f32 %0, %1, %2" : "=v"(r) : "v"(lo), "v"(hi));
    return r;
}
__device__ __forceinline__ void gld_lds16(const u16* src, u16* lds) {
    __builtin_amdgcn_global_load_lds(
        (const __attribute__((address_space(1))) void*)src,
        (__attribute__((address_space(3))) void*)lds, 16, 0, 0);
}

// ---------------------------------------------------------------------------
// Fused projections, one launch (z=0: q&k, z=1..4: v chunk of 32 channels).
// (unchanged from passing round 6)
// ---------------------------------------------------------------------------
__global__ __launch_bounds__(256) void proj_all_kernel(
    const float* __restrict__ x,
    const float* __restrict__ wq, const float* __restrict__ bq,
    const float* __restrict__ wk, const float* __restrict__ bk,
    const float* __restrict__ wv, const float* __restrict__ bv,
    u16* __restrict__ Qb, u16* __restrict__ Kb, u16* __restrict__ Vb)
{
    __shared__ float smem[12800];   // 51.2 KB, carved per-branch
    const int tid = threadIdx.x;
    const int b   = blockIdx.y;
    const int nl  = tid & 63;
    const int n   = blockIdx.x * 64 + nl;
    const int ch  = tid >> 6;
    const float* xp = x + ((size_t)b * C_) * N_ + n;

    if (blockIdx.z == 0) {
        // ---------------- q & k projection ----------------
        float* wqs = smem;               // 2048
        float* wks = smem + 2048;        // 2048
        float (*part)[4][64][17] = (float (*)[4][64][17])(smem + 4096);
        for (int i = tid; i < CQ_ * C_; i += 256) { wqs[i] = wq[i]; wks[i] = wk[i]; }
        __syncthreads();

        float qa[CQ_], ka[CQ_];
#pragma unroll
        for (int j = 0; j < CQ_; ++j) { qa[j] = 0.f; ka[j] = 0.f; }
        const int c0 = ch * 32;
        for (int c = c0; c < c0 + 32; ++c) {
            const float xv = xp[(size_t)c * N_];
#pragma unroll
            for (int j = 0; j < CQ_; ++j) {
                qa[j] = fmaf(wqs[j * C_ + c], xv, qa[j]);
                ka[j] = fmaf(wks[j * C_ + c], xv, ka[j]);
            }
        }
#pragma unroll
        for (int j = 0; j < CQ_; ++j) { part[0][ch][nl][j] = qa[j]; part[1][ch][nl][j] = ka[j]; }
        __syncthreads();

        if (tid < 128) {
            const int which = tid >> 6;        // 0 -> q, 1 -> k
            const int n2 = tid & 63;
            const float* bias = which ? bk : bq;
            alignas(16) u16 row[32];
#pragma unroll
            for (int j = 0; j < CQ_; ++j) {
                float v = part[which][0][n2][j] + part[which][1][n2][j]
                        + part[which][2][n2][j] + part[which][3][n2][j] + bias[j];
                u16 h = f2bf(v);
                row[j]       = h;
                row[CQ_ + j] = f2bf(v - bf2f(h));   // lo residual
            }
            u16* dst = (which ? Kb : Qb) + ((size_t)(b * N_ + blockIdx.x * 64 + n2)) * 32;
#pragma unroll
            for (int i = 0; i < 4; ++i)
                reinterpret_cast<uint4*>(dst)[i] = reinterpret_cast<const uint4*>(row)[i];
        }
    } else {
        // ---------------- v projection (32 channels) ----------------
        const int cv0 = (blockIdx.z - 1) * 32;
        float* wvs = smem;               // 4096
        float (*part)[64][33] = (float (*)[64][33])(smem + 4096);
        for (int i = tid; i < 32 * C_; i += 256) wvs[i] = wv[cv0 * C_ + i];
        __syncthreads();

        float acc[32];
#pragma unroll
        for (int j = 0; j < 32; ++j) acc[j] = 0.f;
        const int c0 = ch * 32;
        for (int c = c0; c < c0 + 32; ++c) {
            const float xv = xp[(size_t)c * N_];
#pragma unroll
            for (int j = 0; j < 32; ++j) acc[j] = fmaf(wvs[j * C_ + c], xv, acc[j]);
        }
#pragma unroll
        for (int j = 0; j < 32; ++j) part[ch][nl][j] = acc[j];
        __syncthreads();

        const int jq = tid >> 6;
#pragma unroll
        for (int jj = 0; jj < 8; ++jj) {
            const int j = jq * 8 + jj;
            float v = part[0][nl][j] + part[1][nl][j] + part[2][nl][j] + part[3][nl][j]
                    + bv[cv0 + j];
            Vb[((size_t)(b * C_ + cv0 + j)) * N_ + blockIdx.x * 64 + nl] = f2bf(v);
        }
    }
}

// ---------------------------------------------------------------------------
// Split-KV fused attention — LDS double-buffered 2-phase pipeline.
// Rounds 4/6 showed the compiler sinks register-prefetch loads (VGPR stayed
// at 48/60), leaving ~22 serialized L2 latencies per iter. global_load_lds
// has NO VGPR destination -> cannot be sunk: stage K(4KB)+V(16KB) for tile
// t+1 into LDS[buf^1] while computing tile t from LDS[buf]; one
// vmcnt(0)+barrier per iter.
// Swizzle (both-sides, rule 21): LDS dest linear; global SOURCE pre-XOR'd,
// ds_read applies same XOR.  V [128c][128B]: byte ^= (c&7)<<4 (m214 fix,
// ~conflict-free). K [64kv][64B]: byte ^= (kv&3)<<4 (residual 4-way, only
// 3 reads/iter).  LDS 40KB/block -> 4 blocks/CU.
// Math identical to passing round-4/6 (hi/lo QK, __expf, shfl relayout).
// ---------------------------------------------------------------------------
__global__ __launch_bounds__(256, 4) void attn_split_kernel(
    const u16* __restrict__ Qb, const u16* __restrict__ Kb, const u16* __restrict__ Vb,
    u16* __restrict__ Opart, float* __restrict__ Lpart)
{
    __shared__ __align__(16) u16 Kt[2][KVBLK * 32];    // [kv][32d] swz (kv&3)<<4
    __shared__ __align__(16) u16 Vt[2][C_ * KVBLK];    // [c][64kv] swz (c&7)<<4

    const int tid  = threadIdx.x;
    const int lane = tid & 63;
    const int l16  = lane & 15;
    const int g    = lane >> 4;       // 0..3
    const int wave = tid >> 6;        // 0..3 — owns q-cols n0+16*wave..+15
    const int b    = blockIdx.y;
    const int n0   = blockIdx.x * 64;
    const int s    = blockIdx.z;
    const int ms   = s * MPER;

    // Q B-fragment: B[k=d][col=n], d = 8g..8g+7 of [hi|lo]
    const int qn = n0 + wave * 16 + l16;
    const s16x8 qf = ld8bf(Qb + ((size_t)(b * N_ + qn)) * 32 + 8 * g);

    // ---- staging source addresses (pre-swizzled global, linear LDS) ----
    // K: thread tid -> LDS byte tid*16; kv = tid>>2, col byte (tid&3)*16
    const int kv_s   = tid >> 2;
    const int kcol_s = ((tid & 3) * 16) ^ ((kv_s & 3) << 4);
    const u16* ksrc0 = Kb + ((size_t)b * N_ + kv_s) * 32 + (kcol_s >> 1);
    // V call i: LDS byte i*4096 + tid*16; c = i*32 + tid>>3, col byte (tid&7)*16
    const int vc_s   = tid >> 3;                     // + i*32
    const u16* vsrc0[4];
#pragma unroll
    for (int i = 0; i < 4; ++i) {
        const int c_i  = i * 32 + vc_s;
        const int vcol = ((tid & 7) * 16) ^ ((c_i & 7) << 4);
        vsrc0[i] = Vb + ((size_t)(b * C_ + c_i)) * N_ + (vcol >> 1);
    }

    const bool hig = (g >= 2);
    const bool mid = (g == 1) || (g == 2);

    f32x4 acc[8];
#pragma unroll
    for (int cg = 0; cg < 8; ++cg) acc[cg] = {};
    float lpart = 0.f;

    // ---- prologue: stage tile 0 into buf 0 ----
    gld_lds16(ksrc0 + (size_t)ms * 32, &Kt[0][wave * 512]);
#pragma unroll
    for (int i = 0; i < 4; ++i)
        gld_lds16(vsrc0[i] + ms, &Vt[0][i * 2048 + wave * 512]);
    asm volatile("s_waitcnt vmcnt(0)" ::: "memory");
    __syncthreads();

    int cur = 0;
    for (int t = 0; t < MPER / KVBLK; ++t) {
        // ---- stage tile t+1 into buf^1 (fire-and-forget DMA) ----
        if (t + 1 < MPER / KVBLK) {
            const int mn = ms + (t + 1) * KVBLK;
            gld_lds16(ksrc0 + (size_t)mn * 32, &Kt[cur ^ 1][wave * 512]);
#pragma unroll
            for (int i = 0; i < 4; ++i)
                gld_lds16(vsrc0[i] + mn, &Vt[cur ^ 1][i * 2048 + wave * 512]);
        }

        // ---- S^T = K . Q^T from Kt[cur] ----
        const u16* ktb = &Kt[cur][0];
        f32x4 sacc[4];
#pragma unroll
        for (int mg = 0; mg < 4; ++mg) {
            const int kv  = 16 * mg + l16;
            const int swz = (kv & 3) << 4;
            const s16x8 kf1 = ld8bf(ktb + kv * 32 + (((16 * (g & 1)) ^ swz) >> 1));
            s16x8 kf2 = {};
            if (g < 2) kf2 = ld8bf(ktb + kv * 32 + (((32 + 16 * g) ^ swz) >> 1));
            f32x4 z = {};
            z = __builtin_amdgcn_mfma_f32_16x16x32_bf16(kf1, qf, z, 0, 0, 0);
            z = __builtin_amdgcn_mfma_f32_16x16x32_bf16(kf2, qf, z, 0, 0, 0);
            sacc[mg] = z;
        }

        // ---- P = exp(S^T); denominator in f32 ----
        float p[4][4];
#pragma unroll
        for (int mg = 0; mg < 4; ++mg) {
#pragma unroll
            for (int i = 0; i < 4; ++i) {
                p[mg][i] = __expf(sacc[mg][i]);
                lpart += p[mg][i];
            }
        }

        // ---- per 32-row slice: in-register relayout, then PV from Vt[cur] ----
        const u16* vtb = &Vt[cur][0];
        const int vswz = (l16 & 7) << 4;
#pragma unroll
        for (int ss = 0; ss < 2; ++ss) {
            const u32 a0 = cvtpk_bf16(p[2 * ss][0],     p[2 * ss][1]);
            const u32 b0 = cvtpk_bf16(p[2 * ss][2],     p[2 * ss][3]);
            const u32 a1 = cvtpk_bf16(p[2 * ss + 1][0], p[2 * ss + 1][1]);
            const u32 b1 = cvtpk_bf16(p[2 * ss + 1][2], p[2 * ss + 1][3]);

            const u32 mA = (u32)__shfl_xor((int)(hig ? a0 : a1), 32);
            const u32 mB = (u32)__shfl_xor((int)(hig ? b0 : b1), 32);
            const u32 oA = hig ? a1 : a0;
            const u32 oB = hig ? b1 : b0;
            const u32 eA = mid ? mA : oA;
            const u32 eB = mid ? mB : oB;
            const u32 vA = mid ? oA : mA;
            const u32 vB = mid ? oB : mB;
            const u32 xA = (u32)__shfl_xor((int)vA, 16);
            const u32 xB = (u32)__shfl_xor((int)vB, 16);
            u32x4 w;
            w[0] = (g & 1) ? xA : eA;
            w[1] = (g & 1) ? xB : eB;
            w[2] = (g & 1) ? eA : xA;
            w[3] = (g & 1) ? eB : xB;
            const s16x8 pf = __builtin_bit_cast(s16x8, w);
            const int vcol = (64 * ss + 16 * g) ^ vswz;      // byte col in V row
#pragma unroll
            for (int cg = 0; cg < 8; ++cg) {
                const int c = 16 * cg + l16;
                const s16x8 vf = ld8bf(vtb + c * 64 + (vcol >> 1));
                acc[cg] = __builtin_amdgcn_mfma_f32_16x16x32_bf16(vf, pf, acc[cg], 0, 0, 0);
            }
        }

        // ---- tile t+1 staged? drain DMA, flip buffers ----
        asm volatile("s_waitcnt vmcnt(0)" ::: "memory");
        __syncthreads();
        cur ^= 1;
    }

    // ---- epilogue: store partial l and unnormalized partial O (bf16) ----
    lpart += __shfl_xor(lpart, 16);
    lpart += __shfl_xor(lpart, 32);
    const size_t sb = (size_t)(s * B_ + b);
    if (lane < 16) Lpart[sb * N_ + n0 + wave * 16 + l16] = lpart;

    const int n = n0 + wave * 16 + l16;
#pragma unroll
    for (int cg = 0; cg < 8; ++cg) {
#pragma unroll
        for (int i = 0; i < 4; ++i) {
            const int c = 16 * cg + 4 * g + i;
            Opart[(sb * C_ + c) * N_ + n] = f2bf(acc[cg][i]);
        }
    }
}

// ---------------------------------------------------------------------------
// Combine splits: out = gamma * (sum_s Opart) / (sum_s Lpart) + x.
// ---------------------------------------------------------------------------
__global__ __launch_bounds__(256) void reduce_kernel(
    const u16* __restrict__ Opart, const float* __restrict__ Lpart,
    const float* __restrict__ x, const float* __restrict__ gamma,
    float* __restrict__ out)
{
    const int t  = blockIdx.x * 256 + threadIdx.x;      // 524288 threads
    const size_t e0 = (size_t)t * 4;                    // < B*C*N = 2^21
    const int n = (int)(e0 & (N_ - 1));
    const int c = (int)((e0 >> 12) & (C_ - 1));
    const int b = (int)(e0 >> 19);

    float o0 = 0.f, o1 = 0.f, o2 = 0.f, o3 = 0.f;
    f32x4 l = {};
#pragma unroll
    for (int s = 0; s < SPLIT; ++s) {
        const size_t sb = (size_t)(s * B_ + b);
        const u16x4 ov = *reinterpret_cast<const u16x4*>(Opart + (sb * C_ + c) * N_ + n);
        const f32x4 lv = *reinterpret_cast<const f32x4*>(Lpart + sb * N_ + n);
        o0 += bf2f(ov[0]); o1 += bf2f(ov[1]); o2 += bf2f(ov[2]); o3 += bf2f(ov[3]);
        l += lv;
    }
    const float gm = gamma[0];
    const f32x4 xv = *reinterpret_cast<const f32x4*>(x + e0);
    f32x4 r;
    r[0] = gm * o0 / l[0] + xv[0];
    r[1] = gm * o1 / l[1] + xv[1];
    r[2] = gm * o2 / l[2] + xv[2];
    r[3] = gm * o3 / l[3] + xv[3];
    *reinterpret_cast<f32x4*>(out + e0) = r;
}

// ---------------------------------------------------------------------------
extern "C" void kernel_launch(void* const* d_in, const int* in_sizes, int n_in,
                              void* d_out, int out_size, void* d_ws, size_t ws_size,
                              hipStream_t stream)
{
    const float* x     = (const float*)d_in[0];
    const float* wq    = (const float*)d_in[1];
    const float* bq    = (const float*)d_in[2];
    const float* wk    = (const float*)d_in[3];
    const float* bk    = (const float*)d_in[4];
    const float* wv    = (const float*)d_in[5];
    const float* bv    = (const float*)d_in[6];
    const float* gamma = (const float*)d_in[7];
    float* out = (float*)d_out;

    // ws layout (~22.5 MB): Qb 1MB | Kb 1MB | Vb 4MB | Opart 16MB | Lpart 256KB
    u16* Qb = (u16*)d_ws;                               // (B,N,32)  [hi|lo]
    u16* Kb = Qb + (size_t)B_ * N_ * 32;                // (B,N,32)  [hi|lo]
    u16* Vb = Kb + (size_t)B_ * N_ * 32;                // (B,C,N)   bf16
    u16* Opart = Vb + (size_t)B_ * C_ * N_;             // (SPLIT,B,C,N) bf16
    float* Lpart = (float*)(Opart + (size_t)SPLIT * B_ * C_ * N_);  // (SPLIT,B,N)

    proj_all_kernel<<<dim3(N_ / 64, B_, 5), 256, 0, stream>>>(
        x, wq, bq, wk, bk, wv, bv, Qb, Kb, Vb);
    attn_split_kernel<<<dim3(N_ / 64, B_, SPLIT), 256, 0, stream>>>(
        Qb, Kb, Vb, Opart, Lpart);
    reduce_kernel<<<(B_ * C_ * N_ / 4) / 256, 256, 0, stream>>>(
        Opart, Lpart, x, gamma, out);
}

// Round 9
// 74.654 us; speedup vs baseline: 2.4433x; 1.0546x over previous
//
#include <hip/hip_runtime.h>

// Problem constants (fixed by setup_inputs)
#define B_    4
#define C_    128
#define CQ_   16
#define N_    4096
#define SPLIT 4
#define MPER  (N_ / SPLIT)   // 1024 kv-positions per split block
#define KVBLK 64
#define NT    (MPER / KVBLK) // 16 kv-tiles per block

typedef short          s16x8 __attribute__((ext_vector_type(8)));
typedef unsigned short u16x4 __attribute__((ext_vector_type(4)));
typedef unsigned int   u32x4 __attribute__((ext_vector_type(4)));
typedef float          f32x4 __attribute__((ext_vector_type(4)));
typedef unsigned short u16;
typedef unsigned int   u32;

__device__ __forceinline__ u16 f2bf(float f) {
    unsigned int u = __builtin_bit_cast(unsigned int, f);
    u += 0x7fffu + ((u >> 16) & 1u);           // round-to-nearest-even
    return (u16)(u >> 16);
}
__device__ __forceinline__ float bf2f(u16 h) {
    unsigned int u = ((unsigned int)h) << 16;
    return __builtin_bit_cast(float, u);
}
__device__ __forceinline__ s16x8 ld8bf(const u16* p) {
    return *reinterpret_cast<const s16x8*>(p);
}
__device__ __forceinline__ u32 cvtpk_bf16(float lo, float hi) {
    u32 r;
    asm("v_cvt_pk_bf16_f32 %0, %1, %2" : "=v"(r) : "v"(lo), "v"(hi));
    return r;
}
__device__ __forceinline__ void gld_lds16(const u16* src, u16* lds) {
    __builtin_amdgcn_global_load_lds(
        (const __attribute__((address_space(1))) void*)src,
        (__attribute__((address_space(3))) void*)lds, 16, 0, 0);
}

// ---------------------------------------------------------------------------
// Fused projections, one launch (z=0: q&k, z=1..4: v chunk of 32 channels).
// (unchanged — passing since round 2)
// ---------------------------------------------------------------------------
__global__ __launch_bounds__(256) void proj_all_kernel(
    const float* __restrict__ x,
    const float* __restrict__ wq, const float* __restrict__ bq,
    const float* __restrict__ wk, const float* __restrict__ bk,
    const float* __restrict__ wv, const float* __restrict__ bv,
    u16* __restrict__ Qb, u16* __restrict__ Kb, u16* __restrict__ Vb)
{
    __shared__ float smem[12800];   // 51.2 KB, carved per-branch
    const int tid = threadIdx.x;
    const int b   = blockIdx.y;
    const int nl  = tid & 63;
    const int n   = blockIdx.x * 64 + nl;
    const int ch  = tid >> 6;
    const float* xp = x + ((size_t)b * C_) * N_ + n;

    if (blockIdx.z == 0) {
        // ---------------- q & k projection ----------------
        float* wqs = smem;               // 2048
        float* wks = smem + 2048;        // 2048
        float (*part)[4][64][17] = (float (*)[4][64][17])(smem + 4096);
        for (int i = tid; i < CQ_ * C_; i += 256) { wqs[i] = wq[i]; wks[i] = wk[i]; }
        __syncthreads();

        float qa[CQ_], ka[CQ_];
#pragma unroll
        for (int j = 0; j < CQ_; ++j) { qa[j] = 0.f; ka[j] = 0.f; }
        const int c0 = ch * 32;
        for (int c = c0; c < c0 + 32; ++c) {
            const float xv = xp[(size_t)c * N_];
#pragma unroll
            for (int j = 0; j < CQ_; ++j) {
                qa[j] = fmaf(wqs[j * C_ + c], xv, qa[j]);
                ka[j] = fmaf(wks[j * C_ + c], xv, ka[j]);
            }
        }
#pragma unroll
        for (int j = 0; j < CQ_; ++j) { part[0][ch][nl][j] = qa[j]; part[1][ch][nl][j] = ka[j]; }
        __syncthreads();

        if (tid < 128) {
            const int which = tid >> 6;        // 0 -> q, 1 -> k
            const int n2 = tid & 63;
            const float* bias = which ? bk : bq;
            alignas(16) u16 row[32];
#pragma unroll
            for (int j = 0; j < CQ_; ++j) {
                float v = part[which][0][n2][j] + part[which][1][n2][j]
                        + part[which][2][n2][j] + part[which][3][n2][j] + bias[j];
                u16 h = f2bf(v);
                row[j]       = h;
                row[CQ_ + j] = f2bf(v - bf2f(h));   // lo residual
            }
            u16* dst = (which ? Kb : Qb) + ((size_t)(b * N_ + blockIdx.x * 64 + n2)) * 32;
#pragma unroll
            for (int i = 0; i < 4; ++i)
                reinterpret_cast<uint4*>(dst)[i] = reinterpret_cast<const uint4*>(row)[i];
        }
    } else {
        // ---------------- v projection (32 channels) ----------------
        const int cv0 = (blockIdx.z - 1) * 32;
        float* wvs = smem;               // 4096
        float (*part)[64][33] = (float (*)[64][33])(smem + 4096);
        for (int i = tid; i < 32 * C_; i += 256) wvs[i] = wv[cv0 * C_ + i];
        __syncthreads();

        float acc[32];
#pragma unroll
        for (int j = 0; j < 32; ++j) acc[j] = 0.f;
        const int c0 = ch * 32;
        for (int c = c0; c < c0 + 32; ++c) {
            const float xv = xp[(size_t)c * N_];
#pragma unroll
            for (int j = 0; j < 32; ++j) acc[j] = fmaf(wvs[j * C_ + c], xv, acc[j]);
        }
#pragma unroll
        for (int j = 0; j < 32; ++j) part[ch][nl][j] = acc[j];
        __syncthreads();

        const int jq = tid >> 6;
#pragma unroll
        for (int jj = 0; jj < 8; ++jj) {
            const int j = jq * 8 + jj;
            float v = part[0][nl][j] + part[1][nl][j] + part[2][nl][j] + part[3][nl][j]
                    + bv[cv0 + j];
            Vb[((size_t)(b * C_ + cv0 + j)) * N_ + blockIdx.x * 64 + nl] = f2bf(v);
        }
    }
}

// ---------------------------------------------------------------------------
// Split-KV fused attention, LDS double-buffered DMA pipeline.
// Round-9 = round-8 structure with the V-offset bug fixed: ss=1's column is
// (64 + 16g) ^ vswz computed as a FULL XOR (voffB), not voffA + 32 — adding
// across swizzle bit 6 carried into bit 7 (+1 V row) for lanes with l16&4.
// Wave owns 32 q-cols: K/V fragments each feed 2 MFMAs (halves LDS traffic
// per q). Literal buffer indices; setprio around MFMA clusters.
// ---------------------------------------------------------------------------
__global__ __launch_bounds__(256, 2) void attn_split_kernel(
    const u16* __restrict__ Qb, const u16* __restrict__ Kb, const u16* __restrict__ Vb,
    u16* __restrict__ Opart, float* __restrict__ Lpart)
{
    __shared__ __align__(16) u16 Kt[2][KVBLK * 32];    // [kv][32d] swz (kv&3)<<4
    __shared__ __align__(16) u16 Vt[2][C_ * KVBLK];    // [c][64kv] swz (c&7)<<4

    const int tid  = threadIdx.x;
    const int lane = tid & 63;
    const int l16  = lane & 15;
    const int g    = lane >> 4;       // 0..3
    const int wave = tid >> 6;        // 0..3 — owns q-cols n0+32*wave..+31
    const int b    = blockIdx.y;
    const int n0   = blockIdx.x * 128;
    const int s    = blockIdx.z;
    const int ms   = s * MPER;

    // Q B-fragments for the wave's two 16-col groups
    const int qn = n0 + wave * 32 + l16;
    const s16x8 qf0 = ld8bf(Qb + ((size_t)(b * N_ + qn)) * 32 + 8 * g);
    const s16x8 qf1 = ld8bf(Qb + ((size_t)(b * N_ + qn + 16)) * 32 + 8 * g);

    // ---- staging source addresses (pre-swizzled global, linear LDS) ----
    const int kv_s   = tid >> 2;
    const int kcol_s = ((tid & 3) * 16) ^ ((kv_s & 3) << 4);
    const u16* ksrc0 = Kb + ((size_t)b * N_ + kv_s) * 32 + (kcol_s >> 1);
    const int vc_s   = tid >> 3;                     // + i*32
    const u16* vsrc0[4];
#pragma unroll
    for (int i = 0; i < 4; ++i) {
        const int c_i  = i * 32 + vc_s;
        const int vcol = ((tid & 7) * 16) ^ ((c_i & 7) << 4);
        vsrc0[i] = Vb + ((size_t)(b * C_ + c_i)) * N_ + (vcol >> 1);
    }

    // ---- per-lane LDS read offsets (u16 units; loop-invariant) ----
    const int kswz  = (l16 & 3) << 4;
    const int vswz  = (l16 & 7) << 4;
    const int koff1 = l16 * 32 + (((16 * (g & 1)) ^ kswz) >> 1);
    const int koff2 = l16 * 32 + (((32 + 16 * g) ^ kswz) >> 1);   // g<2 only
    const int voffA = l16 * 64 + (((16 * g) ^ vswz) >> 1);        // ss=0 cols
    const int voffB = l16 * 64 + (((64 + 16 * g) ^ vswz) >> 1);   // ss=1 cols (full XOR!)

    const bool hig = (g >= 2);
    const bool mid = (g == 1) || (g == 2);

    f32x4 acc0[8], acc1[8];
#pragma unroll
    for (int cg = 0; cg < 8; ++cg) { acc0[cg] = {}; acc1[cg] = {}; }
    float lp0 = 0.f, lp1 = 0.f;

    // In-register S->P relayout (verified lane algebra, rounds 4/6/7)
    auto relayout = [&](const float (&p)[4][4], int ss) -> s16x8 {
        const u32 a0 = cvtpk_bf16(p[2 * ss][0],     p[2 * ss][1]);
        const u32 b0 = cvtpk_bf16(p[2 * ss][2],     p[2 * ss][3]);
        const u32 a1 = cvtpk_bf16(p[2 * ss + 1][0], p[2 * ss + 1][1]);
        const u32 b1 = cvtpk_bf16(p[2 * ss + 1][2], p[2 * ss + 1][3]);
        const u32 mA = (u32)__shfl_xor((int)(hig ? a0 : a1), 32);
        const u32 mB = (u32)__shfl_xor((int)(hig ? b0 : b1), 32);
        const u32 oA = hig ? a1 : a0;
        const u32 oB = hig ? b1 : b0;
        const u32 eA = mid ? mA : oA;
        const u32 eB = mid ? mB : oB;
        const u32 vA = mid ? oA : mA;
        const u32 vB = mid ? oB : mB;
        const u32 xA = (u32)__shfl_xor((int)vA, 16);
        const u32 xB = (u32)__shfl_xor((int)vB, 16);
        u32x4 w;
        w[0] = (g & 1) ? xA : eA;
        w[1] = (g & 1) ? xB : eB;
        w[2] = (g & 1) ? eA : xA;
        w[3] = (g & 1) ? eB : xB;
        return __builtin_bit_cast(s16x8, w);
    };

    auto body = [&](int t, int buf) {
        // ---- stage tile t+1 into the other buffer (fire-and-forget DMA) ----
        if (t + 1 < NT) {
            const int mn = ms + (t + 1) * KVBLK;
            gld_lds16(ksrc0 + (size_t)mn * 32, &Kt[buf ^ 1][wave * 512]);
#pragma unroll
            for (int i = 0; i < 4; ++i)
                gld_lds16(vsrc0[i] + mn, &Vt[buf ^ 1][i * 2048 + wave * 512]);
        }
        const u16* ktb = &Kt[buf][0];
        const u16* vtb = &Vt[buf][0];

        // ---- S^T = K . Q^T for both col-groups (K-frags reused) ----
        f32x4 s0[4], s1[4];
        __builtin_amdgcn_s_setprio(1);
#pragma unroll
        for (int mg = 0; mg < 4; ++mg) {
            const s16x8 kf1 = ld8bf(ktb + koff1 + mg * 512);
            s16x8 kf2 = {};
            if (g < 2) kf2 = ld8bf(ktb + koff2 + mg * 512);
            f32x4 z0 = {}, z1 = {};
            z0 = __builtin_amdgcn_mfma_f32_16x16x32_bf16(kf1, qf0, z0, 0, 0, 0);
            z0 = __builtin_amdgcn_mfma_f32_16x16x32_bf16(kf2, qf0, z0, 0, 0, 0);
            z1 = __builtin_amdgcn_mfma_f32_16x16x32_bf16(kf1, qf1, z1, 0, 0, 0);
            z1 = __builtin_amdgcn_mfma_f32_16x16x32_bf16(kf2, qf1, z1, 0, 0, 0);
            s0[mg] = z0; s1[mg] = z1;
        }
        __builtin_amdgcn_s_setprio(0);

        // ---- P = exp(S^T), relayout to B-frags (per col-group) ----
        s16x8 pf00, pf01, pf10, pf11;
        {
            float p[4][4];
#pragma unroll
            for (int mg = 0; mg < 4; ++mg)
#pragma unroll
                for (int i = 0; i < 4; ++i) { p[mg][i] = __expf(s0[mg][i]); lp0 += p[mg][i]; }
            pf00 = relayout(p, 0); pf01 = relayout(p, 1);
        }
        {
            float p[4][4];
#pragma unroll
            for (int mg = 0; mg < 4; ++mg)
#pragma unroll
                for (int i = 0; i < 4; ++i) { p[mg][i] = __expf(s1[mg][i]); lp1 += p[mg][i]; }
            pf10 = relayout(p, 0); pf11 = relayout(p, 1);
        }

        // ---- O^T += V^T . P^T (each V-frag feeds both col-groups) ----
        __builtin_amdgcn_s_setprio(1);
#pragma unroll
        for (int cg = 0; cg < 8; ++cg) {
            const s16x8 vfa = ld8bf(vtb + voffA + cg * 1024);
            acc0[cg] = __builtin_amdgcn_mfma_f32_16x16x32_bf16(vfa, pf00, acc0[cg], 0, 0, 0);
            acc1[cg] = __builtin_amdgcn_mfma_f32_16x16x32_bf16(vfa, pf10, acc1[cg], 0, 0, 0);
            const s16x8 vfb = ld8bf(vtb + voffB + cg * 1024);
            acc0[cg] = __builtin_amdgcn_mfma_f32_16x16x32_bf16(vfb, pf01, acc0[cg], 0, 0, 0);
            acc1[cg] = __builtin_amdgcn_mfma_f32_16x16x32_bf16(vfb, pf11, acc1[cg], 0, 0, 0);
        }
        __builtin_amdgcn_s_setprio(0);

        // ---- drain DMA for tile t+1, flip ----
        asm volatile("s_waitcnt vmcnt(0)" ::: "memory");
        __syncthreads();
    };

    // ---- prologue: stage tile 0 into buf 0 ----
    gld_lds16(ksrc0 + (size_t)ms * 32, &Kt[0][wave * 512]);
#pragma unroll
    for (int i = 0; i < 4; ++i)
        gld_lds16(vsrc0[i] + ms, &Vt[0][i * 2048 + wave * 512]);
    asm volatile("s_waitcnt vmcnt(0)" ::: "memory");
    __syncthreads();

    for (int tt = 0; tt < NT / 2; ++tt) {
        body(2 * tt, 0);         // literal buffer index -> base+imm ds addrs
        body(2 * tt + 1, 1);
    }

    // ---- epilogue: store partial l and unnormalized partial O (bf16) ----
    lp0 += __shfl_xor(lp0, 16);  lp0 += __shfl_xor(lp0, 32);
    lp1 += __shfl_xor(lp1, 16);  lp1 += __shfl_xor(lp1, 32);
    const size_t sb = (size_t)(s * B_ + b);
    if (lane < 16) {
        Lpart[sb * N_ + n0 + wave * 32 + l16]      = lp0;
        Lpart[sb * N_ + n0 + wave * 32 + 16 + l16] = lp1;
    }

    const int na = n0 + wave * 32 + l16;
#pragma unroll
    for (int cg = 0; cg < 8; ++cg) {
#pragma unroll
        for (int i = 0; i < 4; ++i) {
            const int c = 16 * cg + 4 * g + i;
            Opart[(sb * C_ + c) * N_ + na]      = f2bf(acc0[cg][i]);
            Opart[(sb * C_ + c) * N_ + na + 16] = f2bf(acc1[cg][i]);
        }
    }
}

// ---------------------------------------------------------------------------
// Combine splits: out = gamma * (sum_s Opart) / (sum_s Lpart) + x.
// ---------------------------------------------------------------------------
__global__ __launch_bounds__(256) void reduce_kernel(
    const u16* __restrict__ Opart, const float* __restrict__ Lpart,
    const float* __restrict__ x, const float* __restrict__ gamma,
    float* __restrict__ out)
{
    const int t  = blockIdx.x * 256 + threadIdx.x;      // 524288 threads
    const size_t e0 = (size_t)t * 4;                    // < B*C*N = 2^21
    const int n = (int)(e0 & (N_ - 1));
    const int c = (int)((e0 >> 12) & (C_ - 1));
    const int b = (int)(e0 >> 19);

    float o0 = 0.f, o1 = 0.f, o2 = 0.f, o3 = 0.f;
    f32x4 l = {};
#pragma unroll
    for (int s = 0; s < SPLIT; ++s) {
        const size_t sb = (size_t)(s * B_ + b);
        const u16x4 ov = *reinterpret_cast<const u16x4*>(Opart + (sb * C_ + c) * N_ + n);
        const f32x4 lv = *reinterpret_cast<const f32x4*>(Lpart + sb * N_ + n);
        o0 += bf2f(ov[0]); o1 += bf2f(ov[1]); o2 += bf2f(ov[2]); o3 += bf2f(ov[3]);
        l += lv;
    }
    const float gm = gamma[0];
    const f32x4 xv = *reinterpret_cast<const f32x4*>(x + e0);
    f32x4 r;
    r[0] = gm * o0 / l[0] + xv[0];
    r[1] = gm * o1 / l[1] + xv[1];
    r[2] = gm * o2 / l[2] + xv[2];
    r[3] = gm * o3 / l[3] + xv[3];
    *reinterpret_cast<f32x4*>(out + e0) = r;
}

// ---------------------------------------------------------------------------
extern "C" void kernel_launch(void* const* d_in, const int* in_sizes, int n_in,
                              void* d_out, int out_size, void* d_ws, size_t ws_size,
                              hipStream_t stream)
{
    const float* x     = (const float*)d_in[0];
    const float* wq    = (const float*)d_in[1];
    const float* bq    = (const float*)d_in[2];
    const float* wk    = (const float*)d_in[3];
    const float* bk    = (const float*)d_in[4];
    const float* wv    = (const float*)d_in[5];
    const float* bv    = (const float*)d_in[6];
    const float* gamma = (const float*)d_in[7];
    float* out = (float*)d_out;

    // ws layout (~22.5 MB): Qb 1MB | Kb 1MB | Vb 4MB | Opart 16MB | Lpart 256KB
    u16* Qb = (u16*)d_ws;                               // (B,N,32)  [hi|lo]
    u16* Kb = Qb + (size_t)B_ * N_ * 32;                // (B,N,32)  [hi|lo]
    u16* Vb = Kb + (size_t)B_ * N_ * 32;                // (B,C,N)   bf16
    u16* Opart = Vb + (size_t)B_ * C_ * N_;             // (SPLIT,B,C,N) bf16
    float* Lpart = (float*)(Opart + (size_t)SPLIT * B_ * C_ * N_);  // (SPLIT,B,N)

    proj_all_kernel<<<dim3(N_ / 64, B_, 5), 256, 0, stream>>>(
        x, wq, bq, wk, bk, wv, bv, Qb, Kb, Vb);
    attn_split_kernel<<<dim3(N_ / 128, B_, SPLIT), 256, 0, stream>>>(
        Qb, Kb, Vb, Opart, Lpart);
    reduce_kernel<<<(B_ * C_ * N_ / 4) / 256, 256, 0, stream>>>(
        Opart, Lpart, x, gamma, out);
}